// Round 9
// baseline (211.412 us; speedup 1.0000x reference)
//
#include <hip/hip_runtime.h>
#include <math.h>

#define D 64
#define K 512
#define N_TOK (32 * 4096)            // 131072 tokens
#define BLK 256                      // 4 waves
#define TPB 128                      // tokens per block (4 waves x 32)
#define EPS 1e-4f                    // screen ambiguity margin (worst-case err ~1.5e-5)
#define FLAG_CAP 8192

// output layout (all f32, concatenated in reference return order)
#define Q_OFF    0
#define LOSS_OFF 8388608
#define PERP_OFF 8388609
#define ENC_OFF  8388610
#define MIND_OFF 8519682

// ws layout (floats): [0..511] b2 ; [512] S ; [514..1025] counts(int) ;
// [1026] nflag(int) ; [1028..1028+FLAG_CAP) flist(int) ;
// [16384..] bf16 codebook image, 65536 shorts = 128 KB (ws must be >= 192 KB).
// img layout (shorts): off = c*4096 + plane*2048 + f*1024 + rr*32 + g*8
//   c=k>>5 chunk, rr=k&31 code-in-chunk, plane 0=hi 1=lo, f=K-half, g=8-dim group.
// One wave A-fragment load (fixed c,plane,f,sub; lanes col,g) = 1 KB contiguous.

typedef __attribute__((ext_vector_type(8))) short  short8;   // 8 bf16 (4 VGPR)
typedef __attribute__((ext_vector_type(4))) float  f32x4;

__device__ __forceinline__ short f2bf(float x) {             // RNE f32->bf16 bits
    unsigned u = __builtin_bit_cast(unsigned, x);
    unsigned r = (u + 0x7fffu + ((u >> 16) & 1u)) >> 16;
    return (short)r;
}
__device__ __forceinline__ float bf2f(short s) {
    unsigned u = ((unsigned)(unsigned short)s) << 16;
    return __builtin_bit_cast(float, u);
}
__device__ __forceinline__ f32x4 mfma16(short8 a, short8 b, f32x4 c) {
    return __builtin_amdgcn_mfma_f32_16x16x32_bf16(a, b, c, 0, 0, 0);
}

// numpy pairwise_sum, n=64, scalar 8-accumulator order on fl(x*x)
__device__ __forceinline__ float np_sumsq64(const float* x) {
    float r[8];
    #pragma unroll
    for (int j = 0; j < 8; ++j) r[j] = __fmul_rn(x[j], x[j]);
    #pragma unroll
    for (int i = 8; i < 64; i += 8) {
        #pragma unroll
        for (int j = 0; j < 8; ++j)
            r[j] = __fadd_rn(r[j], __fmul_rn(x[i + j], x[i + j]));
    }
    float l = __fadd_rn(__fadd_rn(r[0], r[1]), __fadd_rn(r[2], r[3]));
    float h = __fadd_rn(__fadd_rn(r[4], r[5]), __fadd_rn(r[6], r[7]));
    return __fadd_rn(l, h);
}

__global__ void vq_prep_b2(const float* __restrict__ ew, float* __restrict__ b2) {
    int k = threadIdx.x;
    if (k < K) {
        float row[D];
        const float* p = ew + (size_t)k * D;
        #pragma unroll
        for (int d = 0; d < D; ++d) row[d] = p[d];
        b2[k] = np_sumsq64(row);
    }
}

// bf16 hi/lo codebook image, pre-swizzled to A-fragment order (once per call)
__global__ __launch_bounds__(256) void vq_prep_img(const float* __restrict__ ew,
                                                   short* __restrict__ img) {
    int gt = blockIdx.x * 256 + threadIdx.x;   // 0..4095 = (k, f, g)
    int k = gt >> 3, fg = gt & 7, f = fg >> 2, g = fg & 3;
    int c = k >> 5, rr = k & 31;
    const float* p = ew + (size_t)k * D + f * 32 + g * 8;
    short8 h8, l8;
    #pragma unroll
    for (int j = 0; j < 8; ++j) {
        float x = p[j];
        short hs = f2bf(x);
        h8[j] = hs;
        l8[j] = f2bf(__fsub_rn(x, bf2f(hs)));
    }
    size_t base = (size_t)c * 4096 + f * 1024 + rr * 32 + g * 8;
    *(short8*)(img + base)        = h8;        // hi plane
    *(short8*)(img + base + 2048) = l8;        // lo plane
}

// MFMA screen, no barriers / no staging in the k-loop: A-fragments stream
// from the L1/L2-resident pre-swizzled image; B (32 tokens/wave) in VGPRs.
// Epilogue writes enc + quantized_st directly (gather kernel eliminated).
__global__ __launch_bounds__(BLK, 5) void vq_screen(
    const float* __restrict__ z, const float* __restrict__ ew,
    const short* __restrict__ img, const float* __restrict__ b2,
    float* __restrict__ out, float* __restrict__ S, int* __restrict__ gcnt,
    int* __restrict__ nflag, int* __restrict__ flist)
{
    __shared__ float s_hb2[K];
    __shared__ int   s_cnt[K];

    const int tid  = threadIdx.x;
    const int wid  = tid >> 6, lane = tid & 63;
    const int col  = lane & 15, g = lane >> 4;           // token-col / k-group
    const int tbase = blockIdx.x * TPB + wid * 32;

    s_cnt[tid] = 0;            s_cnt[tid + 256] = 0;
    s_hb2[tid] = 0.5f * b2[tid]; s_hb2[tid + 256] = 0.5f * b2[tid + 256];

    // ---- B-frags: this wave's 32 tokens, hi/lo bf16, plus sum z^2 slices ----
    short8 zhi[2][2], zlo[2][2];
    float zss = 0.f;
    #pragma unroll
    for (int t = 0; t < 2; ++t) {
        const f32x4* zr = (const f32x4*)(z + (size_t)(tbase + t * 16 + col) * D);
        #pragma unroll
        for (int f = 0; f < 2; ++f) {
            f32x4 va = zr[f * 8 + g * 2], vb = zr[f * 8 + g * 2 + 1];
            float v[8] = {va[0], va[1], va[2], va[3], vb[0], vb[1], vb[2], vb[3]};
            short8 h8, l8;
            #pragma unroll
            for (int j = 0; j < 8; ++j) {
                float x = v[j];
                short hs = f2bf(x);
                h8[j] = hs;
                l8[j] = f2bf(__fsub_rn(x, bf2f(hs)));
                zss = fmaf(x, x, zss);
            }
            zhi[t][f] = h8; zlo[t][f] = l8;
        }
    }
    __syncthreads();                                     // s_hb2/s_cnt ready

    float b1[2] = {-1e30f, -1e30f}, b2s[2] = {-1e30f, -1e30f};
    int   k1[2] = {0, 0};

    for (int c = 0; c < 16; ++c) {
        #pragma unroll
        for (int sub = 0; sub < 2; ++sub) {
            const int rr = sub * 16 + col;
            short8 ahi[2], alo[2];
            #pragma unroll
            for (int f = 0; f < 2; ++f) {
                const short* p = img + (size_t)c * 4096 + f * 1024 + rr * 32 + g * 8;
                ahi[f] = *(const short8*)p;
                alo[f] = *(const short8*)(p + 2048);
            }
            const int c0 = c * 32 + sub * 16 + g * 4;    // codes this lane scores
            f32x4 hb = *(const f32x4*)&s_hb2[c0];
            #pragma unroll
            for (int t = 0; t < 2; ++t) {
                f32x4 acc = (f32x4){0.f, 0.f, 0.f, 0.f};
                acc = mfma16(ahi[0], zhi[t][0], acc);
                acc = mfma16(ahi[1], zhi[t][1], acc);
                acc = mfma16(ahi[0], zlo[t][0], acc);
                acc = mfma16(ahi[1], zlo[t][1], acc);
                acc = mfma16(alo[0], zhi[t][0], acc);
                acc = mfma16(alo[1], zhi[t][1], acc);
                #pragma unroll
                for (int r = 0; r < 4; ++r) {
                    float sc = acc[r] - hb[r];
                    if (sc > b1[t]) { b2s[t] = b1[t]; b1[t] = sc; k1[t] = c0 + r; }
                    else            { b2s[t] = fmaxf(b2s[t], sc); }
                }
            }
        }
    }

    // ---- cross-lane merge over the 4 k-groups (xor butterfly -> all lanes) ----
    #pragma unroll
    for (int t = 0; t < 2; ++t) {
        #pragma unroll
        for (int m = 16; m < 64; m <<= 1) {
            float ob = __shfl_xor(b1[t], m);
            float os = __shfl_xor(b2s[t], m);
            int   ok = __shfl_xor(k1[t], m);
            if (ob > b1[t])       { b2s[t] = fmaxf(b1[t], os); b1[t] = ob; k1[t] = ok; }
            else if (ob == b1[t]) { b2s[t] = b1[t]; if (ok < k1[t]) k1[t] = ok; }  // tie -> flag
            else                  { b2s[t] = fmaxf(b2s[t], ob); }
        }
    }

    // ---- epilogue: enc + flags (lane<16), quantized_st (all lanes) ----
    #pragma unroll
    for (int t = 0; t < 2; ++t) {
        const int tok = tbase + t * 16 + col;
        if (lane < 16) {
            out[ENC_OFF + tok] = (float)k1[t];
            atomicAdd(&s_cnt[k1[t]], 1);
            if (b1[t] - b2s[t] < EPS) {                  // ambiguous: exact re-check
                int slot = atomicAdd(nflag, 1);
                if (slot < FLAG_CAP) flist[slot] = tok;
            }
        }
        const f32x4* zr = (const f32x4*)(z + (size_t)tok * D);
        #pragma unroll
        for (int f = 0; f < 2; ++f) {
            f32x4 zv0 = zr[f * 8 + g * 2], zv1 = zr[f * 8 + g * 2 + 1];
            const f32x4* er = (const f32x4*)(ew + (size_t)k1[t] * D + f * 32 + g * 8);
            f32x4 e0 = er[0], e1 = er[1], o0, o1;
            #pragma unroll
            for (int r = 0; r < 4; ++r) {
                o0[r] = __fadd_rn(zv0[r], __fsub_rn(e0[r], zv0[r]));
                o1[r] = __fadd_rn(zv1[r], __fsub_rn(e1[r], zv1[r]));
            }
            f32x4* op = (f32x4*)(out + Q_OFF + (size_t)tok * D + f * 32 + g * 8);
            op[0] = o0; op[1] = o1;
        }
    }

    // S = sum ||z||^2 - 2 * sum best_score (loss/mind thresholds are huge)
    float contrib = zss + ((lane < 16) ? -2.f * (b1[0] + b1[1]) : 0.f);
    #pragma unroll
    for (int off = 32; off; off >>= 1) contrib += __shfl_down(contrib, off);
    if (lane == 0) atomicAdd(S, contrib);

    __syncthreads();
    int c0 = s_cnt[tid];       if (c0) atomicAdd(&gcnt[tid], c0);
    int c1 = s_cnt[tid + 256]; if (c1) atomicAdd(&gcnt[tid + 256], c1);
}

// exact numpy-f32 rescan of flagged tokens: one token/wave, code/lane;
// repairs enc, histogram AND the quantized row.
__global__ __launch_bounds__(64) void vq_refine(
    const float* __restrict__ z, const float* __restrict__ ew,
    const float* __restrict__ b2, float* __restrict__ out,
    int* __restrict__ gcnt, const int* __restrict__ nflag,
    const int* __restrict__ flist)
{
    const int lane = threadIdx.x;
    int nf = *nflag; if (nf > FLAG_CAP) nf = FLAG_CAP;

    for (int i = blockIdx.x; i < nf; i += gridDim.x) {
        const int tok = flist[i];
        const int old = (int)out[ENC_OFF + tok];         // read before any write
        float zf[D];
        const float* zrow = z + (size_t)tok * D;
        #pragma unroll
        for (int d = 0; d < D; ++d) zf[d] = zrow[d];
        const float an = np_sumsq64(zf);

        float bd = 1e30f; int bk = 0;
        #pragma unroll 1
        for (int j = 0; j < 8; ++j) {
            const int c = j * 64 + lane;
            const float* e0 = ew + (size_t)c * D;
            float gacc = 0.f;
            #pragma unroll
            for (int d = 0; d < D; ++d) gacc = fmaf(zf[d], e0[d], gacc);
            float dd = fmaf(-2.f, gacc, __fadd_rn(an, b2[c]));
            if (dd < bd) { bd = dd; bk = c; }            // lane-ascending codes
        }
        #pragma unroll
        for (int off = 32; off; off >>= 1) {             // min-d, min-index
            float obd = __shfl_down(bd, off);
            int   obk = __shfl_down(bk, off);
            if (obd < bd || (obd == bd && obk < bk)) { bd = obd; bk = obk; }
        }
        bk = __shfl(bk, 0);

        if (bk != old) {
            float zv = zrow[lane];
            float ev = ew[(size_t)bk * D + lane];
            out[Q_OFF + (size_t)tok * D + lane] = __fadd_rn(zv, __fsub_rn(ev, zv));
            if (lane == 0) {
                out[ENC_OFF + tok] = (float)bk;
                atomicAdd(&gcnt[bk], 1);
                atomicAdd(&gcnt[old], -1);
            }
        }
    }
}

__global__ void vq_fin(const float* __restrict__ S, const int* __restrict__ gcnt,
                       float* __restrict__ out)
{
    __shared__ float red[8];
    int t = threadIdx.x;               // 512 threads, one per code
    float p = (float)gcnt[t] * (1.f / (float)N_TOK);
    float term = p * logf(p + 1e-10f);
    #pragma unroll
    for (int off = 32; off; off >>= 1) term += __shfl_down(term, off);
    if ((t & 63) == 0) red[t >> 6] = term;
    __syncthreads();
    if (t == 0) {
        float s = 0.f;
        #pragma unroll
        for (int i = 0; i < 8; ++i) s += red[i];
        float Sv = S[0];
        out[PERP_OFF] = expf(-s);
        out[LOSS_OFF] = 1.25f * Sv * (1.f / (float)(N_TOK * D));
        out[MIND_OFF] = Sv * (1.f / (float)N_TOK);
    }
}

extern "C" void kernel_launch(void* const* d_in, const int* in_sizes, int n_in,
                              void* d_out, int out_size, void* d_ws, size_t ws_size,
                              hipStream_t stream)
{
    const float* z  = (const float*)d_in[0];
    const float* ew = (const float*)d_in[1];
    float* out = (float*)d_out;
    float* wsf = (float*)d_ws;

    float* Sp    = wsf + 512;
    int*   gcnt  = (int*)(wsf + 514);
    int*   nflag = (int*)(wsf + 1026);
    int*   flist = (int*)(wsf + 1028);
    short* img   = (short*)(wsf + 16384);    // 128 KB bf16 image

    // zero S, counts, flag counter each call (graph replays don't re-poison)
    hipMemsetAsync(wsf + 512, 0, 516 * sizeof(float), stream);

    vq_prep_b2 <<<1, 512, 0, stream>>>(ew, wsf);
    vq_prep_img<<<16, 256, 0, stream>>>(ew, img);
    vq_screen  <<<N_TOK / TPB, BLK, 0, stream>>>(z, ew, img, wsf, out, Sp, gcnt, nflag, flist);
    vq_refine  <<<1024, 64, 0, stream>>>(z, ew, wsf, out, gcnt, nflag, flist);
    vq_fin     <<<1, 512, 0, stream>>>(Sp, gcnt, out);
}

// Round 10
// 202.106 us; speedup vs baseline: 1.0460x; 1.0460x over previous
//
#include <hip/hip_runtime.h>
#include <math.h>

#define D 64
#define K 512
#define N_TOK (32 * 4096)            // 131072 tokens
#define BLK 256                      // 4 waves
#define TPB 128                      // tokens per block (4 waves x 32)
#define EPS 1e-4f                    // screen ambiguity margin (worst-case err ~1.5e-5)
#define FLAG_CAP 8192

// output layout (all f32, concatenated in reference return order)
#define Q_OFF    0
#define LOSS_OFF 8388608
#define PERP_OFF 8388609
#define ENC_OFF  8388610
#define MIND_OFF 8519682

// ws layout (floats): [0..511] b2 ; [512] S ; [514..1025] counts(int) ;
// [1026] nflag(int) ; [1028..1028+FLAG_CAP) flist(int) ;
// [16384..] bf16 codebook image, 65536 shorts = 128 KB (ws must be >= 192 KB).
// img layout (shorts): off = c*4096 + plane*2048 + f*1024 + rr*32 + g*8

typedef __attribute__((ext_vector_type(8))) short  short8;   // 8 bf16 (4 VGPR)
typedef __attribute__((ext_vector_type(4))) float  f32x4;

__device__ __forceinline__ short f2bf(float x) {             // RNE f32->bf16 bits
    unsigned u = __builtin_bit_cast(unsigned, x);
    unsigned r = (u + 0x7fffu + ((u >> 16) & 1u)) >> 16;
    return (short)r;
}
__device__ __forceinline__ float bf2f(short s) {
    unsigned u = ((unsigned)(unsigned short)s) << 16;
    return __builtin_bit_cast(float, u);
}
__device__ __forceinline__ f32x4 mfma16(short8 a, short8 b, f32x4 c) {
    return __builtin_amdgcn_mfma_f32_16x16x32_bf16(a, b, c, 0, 0, 0);
}

// numpy pairwise_sum, n=64, scalar 8-accumulator order on fl(x*x)
__device__ __forceinline__ float np_sumsq64(const float* x) {
    float r[8];
    #pragma unroll
    for (int j = 0; j < 8; ++j) r[j] = __fmul_rn(x[j], x[j]);
    #pragma unroll
    for (int i = 8; i < 64; i += 8) {
        #pragma unroll
        for (int j = 0; j < 8; ++j)
            r[j] = __fadd_rn(r[j], __fmul_rn(x[i + j], x[i + j]));
    }
    float l = __fadd_rn(__fadd_rn(r[0], r[1]), __fadd_rn(r[2], r[3]));
    float h = __fadd_rn(__fadd_rn(r[4], r[5]), __fadd_rn(r[6], r[7]));
    return __fadd_rn(l, h);
}

__global__ __launch_bounds__(256) void vq_prep_b2(const float* __restrict__ ew,
                                                  float* __restrict__ b2) {
    int k = blockIdx.x * 256 + threadIdx.x;
    if (k < K) {
        float row[D];
        const float* p = ew + (size_t)k * D;
        #pragma unroll
        for (int d = 0; d < D; ++d) row[d] = p[d];
        b2[k] = np_sumsq64(row);
    }
}

// bf16 hi/lo codebook image, pre-swizzled to A-fragment order (once per call)
__global__ __launch_bounds__(256) void vq_prep_img(const float* __restrict__ ew,
                                                   short* __restrict__ img) {
    int gt = blockIdx.x * 256 + threadIdx.x;   // 0..4095 = (k, f, g)
    int k = gt >> 3, fg = gt & 7, f = fg >> 2, g = fg & 3;
    int c = k >> 5, rr = k & 31;
    const float* p = ew + (size_t)k * D + f * 32 + g * 8;
    short8 h8, l8;
    #pragma unroll
    for (int j = 0; j < 8; ++j) {
        float x = p[j];
        short hs = f2bf(x);
        h8[j] = hs;
        l8[j] = f2bf(__fsub_rn(x, bf2f(hs)));
    }
    size_t base = (size_t)c * 4096 + f * 1024 + rr * 32 + g * 8;
    *(short8*)(img + base)        = h8;        // hi plane
    *(short8*)(img + base + 2048) = l8;        // lo plane
}

// MFMA screen. Explicit double-buffered prefetch of A-fragments (named reg
// sets -> ~120 VGPR) so the 8 img loads of chunk c+1 stay in flight under
// chunk c's 24 MFMAs + selects. No barriers in the k-loop.
__global__ __launch_bounds__(BLK, 4) void vq_screen(
    const float* __restrict__ z, const float* __restrict__ ew,
    const short* __restrict__ img, const float* __restrict__ b2,
    float* __restrict__ out, float* __restrict__ S, int* __restrict__ gcnt,
    int* __restrict__ nflag, int* __restrict__ flist)
{
    __shared__ float s_hb2[K];
    __shared__ int   s_cnt[K];

    const int tid  = threadIdx.x;
    const int wid  = tid >> 6, lane = tid & 63;
    const int col  = lane & 15, g = lane >> 4;           // token-col / k-group
    const int tbase = blockIdx.x * TPB + wid * 32;

    s_cnt[tid] = 0;            s_cnt[tid + 256] = 0;
    s_hb2[tid] = 0.5f * b2[tid]; s_hb2[tid + 256] = 0.5f * b2[tid + 256];

    // ---- B-frags: this wave's 32 tokens, hi/lo bf16, plus sum z^2 slices ----
    short8 zhi[2][2], zlo[2][2];
    float zss = 0.f;
    #pragma unroll
    for (int t = 0; t < 2; ++t) {
        const f32x4* zr = (const f32x4*)(z + (size_t)(tbase + t * 16 + col) * D);
        #pragma unroll
        for (int f = 0; f < 2; ++f) {
            f32x4 va = zr[f * 8 + g * 2], vb = zr[f * 8 + g * 2 + 1];
            float v[8] = {va[0], va[1], va[2], va[3], vb[0], vb[1], vb[2], vb[3]};
            short8 h8, l8;
            #pragma unroll
            for (int j = 0; j < 8; ++j) {
                float x = v[j];
                short hs = f2bf(x);
                h8[j] = hs;
                l8[j] = f2bf(__fsub_rn(x, bf2f(hs)));
                zss = fmaf(x, x, zss);
            }
            zhi[t][f] = h8; zlo[t][f] = l8;
        }
    }
    __syncthreads();                                     // s_hb2/s_cnt ready

    float b1[2] = {-1e30f, -1e30f}, b2s[2] = {-1e30f, -1e30f};
    int   k1[2] = {0, 0};

#define LOADC(cc, ah, al) do {                                               \
        _Pragma("unroll")                                                    \
        for (int sub_ = 0; sub_ < 2; ++sub_) {                               \
            _Pragma("unroll")                                                \
            for (int f_ = 0; f_ < 2; ++f_) {                                 \
                const short* p_ = img + (size_t)(cc) * 4096 + f_ * 1024      \
                                  + (sub_ * 16 + col) * 32 + g * 8;          \
                ah[sub_ * 2 + f_] = *(const short8*)p_;                      \
                al[sub_ * 2 + f_] = *(const short8*)(p_ + 2048);             \
            }                                                                \
        }                                                                    \
    } while (0)

#define COMPUTE(cc, ah, al) do {                                             \
        _Pragma("unroll")                                                    \
        for (int sub_ = 0; sub_ < 2; ++sub_) {                               \
            const int c0_ = (cc) * 32 + sub_ * 16 + g * 4;                   \
            f32x4 hb_ = *(const f32x4*)&s_hb2[c0_];                          \
            _Pragma("unroll")                                                \
            for (int t_ = 0; t_ < 2; ++t_) {                                 \
                f32x4 acc_ = (f32x4){0.f, 0.f, 0.f, 0.f};                    \
                acc_ = mfma16(ah[sub_*2+0], zhi[t_][0], acc_);               \
                acc_ = mfma16(ah[sub_*2+1], zhi[t_][1], acc_);               \
                acc_ = mfma16(ah[sub_*2+0], zlo[t_][0], acc_);               \
                acc_ = mfma16(ah[sub_*2+1], zlo[t_][1], acc_);               \
                acc_ = mfma16(al[sub_*2+0], zhi[t_][0], acc_);               \
                acc_ = mfma16(al[sub_*2+1], zhi[t_][1], acc_);               \
                _Pragma("unroll")                                            \
                for (int r_ = 0; r_ < 4; ++r_) {                             \
                    float sc_ = acc_[r_] - hb_[r_];                          \
                    if (sc_ > b1[t_]) { b2s[t_] = b1[t_]; b1[t_] = sc_;      \
                                        k1[t_] = c0_ + r_; }                 \
                    else              { b2s[t_] = fmaxf(b2s[t_], sc_); }     \
                }                                                            \
            }                                                                \
        }                                                                    \
    } while (0)

    short8 ah0[4], al0[4], ah1[4], al1[4];
    LOADC(0, ah0, al0);
    #pragma unroll 1
    for (int c = 0; c < 16; c += 2) {
        LOADC(c + 1, ah1, al1);
        COMPUTE(c, ah0, al0);
        if (c + 2 < 16) LOADC(c + 2, ah0, al0);
        COMPUTE(c + 1, ah1, al1);
    }
#undef LOADC
#undef COMPUTE

    // ---- cross-lane merge over the 4 k-groups (xor butterfly -> all lanes) ----
    #pragma unroll
    for (int t = 0; t < 2; ++t) {
        #pragma unroll
        for (int m = 16; m < 64; m <<= 1) {
            float ob = __shfl_xor(b1[t], m);
            float os = __shfl_xor(b2s[t], m);
            int   ok = __shfl_xor(k1[t], m);
            if (ob > b1[t])       { b2s[t] = fmaxf(b1[t], os); b1[t] = ob; k1[t] = ok; }
            else if (ob == b1[t]) { b2s[t] = b1[t]; if (ok < k1[t]) k1[t] = ok; }  // tie -> flag
            else                  { b2s[t] = fmaxf(b2s[t], ob); }
        }
    }

    // ---- epilogue: enc + flags (lane<16), quantized_st (all lanes) ----
    #pragma unroll
    for (int t = 0; t < 2; ++t) {
        const int tok = tbase + t * 16 + col;
        if (lane < 16) {
            out[ENC_OFF + tok] = (float)k1[t];
            atomicAdd(&s_cnt[k1[t]], 1);
            if (b1[t] - b2s[t] < EPS) {                  // ambiguous: exact re-check
                int slot = atomicAdd(nflag, 1);
                if (slot < FLAG_CAP) flist[slot] = tok;
            }
        }
        const f32x4* zr = (const f32x4*)(z + (size_t)tok * D);
        #pragma unroll
        for (int f = 0; f < 2; ++f) {
            f32x4 zv0 = zr[f * 8 + g * 2], zv1 = zr[f * 8 + g * 2 + 1];
            const f32x4* er = (const f32x4*)(ew + (size_t)k1[t] * D + f * 32 + g * 8);
            f32x4 e0 = er[0], e1 = er[1], o0, o1;
            #pragma unroll
            for (int r = 0; r < 4; ++r) {
                o0[r] = __fadd_rn(zv0[r], __fsub_rn(e0[r], zv0[r]));
                o1[r] = __fadd_rn(zv1[r], __fsub_rn(e1[r], zv1[r]));
            }
            f32x4* op = (f32x4*)(out + Q_OFF + (size_t)tok * D + f * 32 + g * 8);
            op[0] = o0; op[1] = o1;
        }
    }

    // S = sum ||z||^2 - 2 * sum best_score (loss/mind thresholds are huge)
    float contrib = zss + ((lane < 16) ? -2.f * (b1[0] + b1[1]) : 0.f);
    #pragma unroll
    for (int off = 32; off; off >>= 1) contrib += __shfl_down(contrib, off);
    if (lane == 0) atomicAdd(S, contrib);

    __syncthreads();
    int c0 = s_cnt[tid];       if (c0) atomicAdd(&gcnt[tid], c0);
    int c1 = s_cnt[tid + 256]; if (c1) atomicAdd(&gcnt[tid + 256], c1);
}

// exact numpy-f32 rescan of flagged tokens. ONE WAVE PER TOKEN (8192 wave
// slots >= FLAG_CAP) — the r8/r9 version ran 1024 single-wave blocks with
// multiple tokens each and was latency-bound at ~4 waves/CU.
__global__ __launch_bounds__(256) void vq_refine(
    const float* __restrict__ z, const float* __restrict__ ew,
    const float* __restrict__ b2, float* __restrict__ out,
    int* __restrict__ gcnt, const int* __restrict__ nflag,
    const int* __restrict__ flist)
{
    const int lane  = threadIdx.x & 63;
    const int wslot = (blockIdx.x << 2) | (threadIdx.x >> 6);   // 0..8191
    int nf = *nflag; if (nf > FLAG_CAP) nf = FLAG_CAP;

    for (int i = wslot; i < nf; i += 8192) {
        const int tok = flist[i];
        const int old = (int)out[ENC_OFF + tok];         // read before any write
        float zf[D];
        const float* zrow = z + (size_t)tok * D;
        #pragma unroll
        for (int d = 0; d < D; ++d) zf[d] = zrow[d];
        const float an = np_sumsq64(zf);

        float bd = 1e30f; int bk = 0;
        #pragma unroll 1
        for (int j = 0; j < 8; ++j) {
            const int c = j * 64 + lane;
            const float* e0 = ew + (size_t)c * D;
            float gacc = 0.f;
            #pragma unroll
            for (int d = 0; d < D; ++d) gacc = fmaf(zf[d], e0[d], gacc);
            float dd = fmaf(-2.f, gacc, __fadd_rn(an, b2[c]));
            if (dd < bd) { bd = dd; bk = c; }            // lane-ascending codes
        }
        #pragma unroll
        for (int off = 32; off; off >>= 1) {             // min-d, min-index
            float obd = __shfl_down(bd, off);
            int   obk = __shfl_down(bk, off);
            if (obd < bd || (obd == bd && obk < bk)) { bd = obd; bk = obk; }
        }
        bk = __shfl(bk, 0);

        if (bk != old) {
            float zv = zrow[lane];
            float ev = ew[(size_t)bk * D + lane];
            out[Q_OFF + (size_t)tok * D + lane] = __fadd_rn(zv, __fsub_rn(ev, zv));
            if (lane == 0) {
                out[ENC_OFF + tok] = (float)bk;
                atomicAdd(&gcnt[bk], 1);
                atomicAdd(&gcnt[old], -1);
            }
        }
    }
}

__global__ void vq_fin(const float* __restrict__ S, const int* __restrict__ gcnt,
                       float* __restrict__ out)
{
    __shared__ float red[8];
    int t = threadIdx.x;               // 512 threads, one per code
    float p = (float)gcnt[t] * (1.f / (float)N_TOK);
    float term = p * logf(p + 1e-10f);
    #pragma unroll
    for (int off = 32; off; off >>= 1) term += __shfl_down(term, off);
    if ((t & 63) == 0) red[t >> 6] = term;
    __syncthreads();
    if (t == 0) {
        float s = 0.f;
        #pragma unroll
        for (int i = 0; i < 8; ++i) s += red[i];
        float Sv = S[0];
        out[PERP_OFF] = expf(-s);
        out[LOSS_OFF] = 1.25f * Sv * (1.f / (float)(N_TOK * D));
        out[MIND_OFF] = Sv * (1.f / (float)N_TOK);
    }
}

extern "C" void kernel_launch(void* const* d_in, const int* in_sizes, int n_in,
                              void* d_out, int out_size, void* d_ws, size_t ws_size,
                              hipStream_t stream)
{
    const float* z  = (const float*)d_in[0];
    const float* ew = (const float*)d_in[1];
    float* out = (float*)d_out;
    float* wsf = (float*)d_ws;

    float* Sp    = wsf + 512;
    int*   gcnt  = (int*)(wsf + 514);
    int*   nflag = (int*)(wsf + 1026);
    int*   flist = (int*)(wsf + 1028);
    short* img   = (short*)(wsf + 16384);    // 128 KB bf16 image

    // zero S, counts, flag counter each call (graph replays don't re-poison)
    hipMemsetAsync(wsf + 512, 0, 516 * sizeof(float), stream);

    vq_prep_b2 <<<2, 256, 0, stream>>>(ew, wsf);
    vq_prep_img<<<16, 256, 0, stream>>>(ew, img);
    vq_screen  <<<N_TOK / TPB, BLK, 0, stream>>>(z, ew, img, wsf, out, Sp, gcnt, nflag, flist);
    vq_refine  <<<2048, 256, 0, stream>>>(z, ew, wsf, out, gcnt, nflag, flist);
    vq_fin     <<<1, 512, 0, stream>>>(Sp, gcnt, out);
}

// Round 11
// 138.757 us; speedup vs baseline: 1.5236x; 1.4565x over previous
//
#include <hip/hip_runtime.h>
#include <math.h>

#define D 64
#define K 512
#define N_TOK (32 * 4096)            // 131072 tokens
#define BLK 256                      // 4 waves
#define TPB 128                      // tokens per block (4 waves x 32)
#define EPS 4e-5f                    // screen ambiguity margin (err bound ~2e-6, 20x slack)
#define FLAG_CAP 8192

// output layout (all f32, concatenated in reference return order)
#define Q_OFF    0
#define LOSS_OFF 8388608
#define PERP_OFF 8388609
#define ENC_OFF  8388610
#define MIND_OFF 8519682

// ws layout (floats): [0..511] b2 ; [512] S ; [514..1025] counts(int) ;
// [1026] nflag(int) ; [1028..1028+FLAG_CAP) flist(int) ;
// [16384..] bf16 codebook image, 65536 shorts = 128 KB (ws >= 192 KB).
// img: chunk c (32 codes) = 512 slots x 16B, slot s = grp*64 + lane,
//   grp = plane*4 + f*2 + sub; slot holds codes k=c*32+sub*16+(lane&15),
//   dims f*32+(lane>>4)*8 .. +8, hi (plane0) or lo (plane1) bf16.
// Wave ds_read of frag (plane,f,sub): addr = base + lane*16 + grp*1024 — linear.

typedef __attribute__((ext_vector_type(8))) short  short8;   // 8 bf16 (4 VGPR)
typedef __attribute__((ext_vector_type(4))) float  f32x4;

__device__ __forceinline__ short f2bf(float x) {             // RNE f32->bf16 bits
    unsigned u = __builtin_bit_cast(unsigned, x);
    unsigned r = (u + 0x7fffu + ((u >> 16) & 1u)) >> 16;
    return (short)r;
}
__device__ __forceinline__ float bf2f(short s) {
    unsigned u = ((unsigned)(unsigned short)s) << 16;
    return __builtin_bit_cast(float, u);
}
__device__ __forceinline__ f32x4 mfma16(short8 a, short8 b, f32x4 c) {
    return __builtin_amdgcn_mfma_f32_16x16x32_bf16(a, b, c, 0, 0, 0);
}

// numpy pairwise_sum, n=64, scalar 8-accumulator order on fl(x*x)
__device__ __forceinline__ float np_sumsq64(const float* x) {
    float r[8];
    #pragma unroll
    for (int j = 0; j < 8; ++j) r[j] = __fmul_rn(x[j], x[j]);
    #pragma unroll
    for (int i = 8; i < 64; i += 8) {
        #pragma unroll
        for (int j = 0; j < 8; ++j)
            r[j] = __fadd_rn(r[j], __fmul_rn(x[i + j], x[i + j]));
    }
    float l = __fadd_rn(__fadd_rn(r[0], r[1]), __fadd_rn(r[2], r[3]));
    float h = __fadd_rn(__fadd_rn(r[4], r[5]), __fadd_rn(r[6], r[7]));
    return __fadd_rn(l, h);
}

__global__ __launch_bounds__(256) void vq_prep_b2(const float* __restrict__ ew,
                                                  float* __restrict__ b2) {
    int k = blockIdx.x * 256 + threadIdx.x;
    if (k < K) {
        float row[D];
        const float* p = ew + (size_t)k * D;
        #pragma unroll
        for (int d = 0; d < D; ++d) row[d] = p[d];
        b2[k] = np_sumsq64(row);
    }
}

// bf16 hi/lo codebook image in LDS-staging slot order (8192 threads)
__global__ __launch_bounds__(256) void vq_prep_img(const float* __restrict__ ew,
                                                   short* __restrict__ img) {
    int gt = blockIdx.x * 256 + threadIdx.x;   // 0..8191
    int c = gt >> 9, s = gt & 511;
    int grp = s >> 6, l = s & 63;
    int plane = grp >> 2, f = (grp >> 1) & 1, sub = grp & 1;
    int k  = c * 32 + sub * 16 + (l & 15);
    int d0 = f * 32 + (l >> 4) * 8;
    const float* p = ew + (size_t)k * D + d0;
    short8 v;
    #pragma unroll
    for (int j = 0; j < 8; ++j) {
        float x = p[j];
        short hs = f2bf(x);
        v[j] = plane ? f2bf(__fsub_rn(x, bf2f(hs))) : hs;
    }
    *(short8*)(img + (size_t)gt * 8) = v;
}

// MFMA screen. A-frags stream global->reg->LDS (double-buffered, one barrier
// per chunk); ds_read_b128 feeds the MFMAs directly, so per-wave persistent
// state is ~50 VGPR and the allocator's 64-VGPR habit stops hurting.
// LDS padded >32KB so the occupancy heuristic targets 4 waves/SIMD (grid is
// 4 blocks/CU anyway) and grants a 128-VGPR budget.
__global__ __launch_bounds__(BLK, 4) void vq_screen(
    const float* __restrict__ z, const float* __restrict__ ew,
    const short* __restrict__ img, const float* __restrict__ b2,
    float* __restrict__ out, float* __restrict__ S, int* __restrict__ gcnt,
    int* __restrict__ nflag, int* __restrict__ flist)
{
    __shared__ __align__(16) short lbuf[2][4096];   // 2 x 8KB chunk buffers
    __shared__ float s_hb2[K];
    __shared__ int   s_cnt[K];
    __shared__ f32x4 s_pad[832];                    // 13.3KB occupancy shaper

    const int tid  = threadIdx.x;
    const int lane = tid & 63;
    const int col  = lane & 15, g = lane >> 4;      // token-col / k-group
    const int tbase = blockIdx.x * TPB + (tid >> 6) * 32;

    { volatile float* vp = (volatile float*)s_pad; vp[tid] = 0.f; }  // keep s_pad

    s_cnt[tid] = 0;              s_cnt[tid + 256] = 0;
    s_hb2[tid] = 0.5f * b2[tid]; s_hb2[tid + 256] = 0.5f * b2[tid + 256];

    // stage chunk 0 (all 512 slots by 256 threads, 2 each)
    {
        short8 a = *(const short8*)(img + (size_t)tid * 8);
        short8 b = *(const short8*)(img + (size_t)(256 + tid) * 8);
        *(short8*)&lbuf[0][(size_t)tid * 8]         = a;
        *(short8*)&lbuf[0][(size_t)(256 + tid) * 8] = b;
    }

    // ---- B-frags: this wave's 32 tokens, hi/lo bf16, plus sum z^2 slices ----
    short8 zhi[2][2], zlo[2][2];
    float zss = 0.f;
    #pragma unroll
    for (int t = 0; t < 2; ++t) {
        const f32x4* zr = (const f32x4*)(z + (size_t)(tbase + t * 16 + col) * D);
        #pragma unroll
        for (int f = 0; f < 2; ++f) {
            f32x4 va = zr[f * 8 + g * 2], vb = zr[f * 8 + g * 2 + 1];
            float v[8] = {va[0], va[1], va[2], va[3], vb[0], vb[1], vb[2], vb[3]};
            short8 h8, l8;
            #pragma unroll
            for (int j = 0; j < 8; ++j) {
                float x = v[j];
                short hs = f2bf(x);
                h8[j] = hs;
                l8[j] = f2bf(__fsub_rn(x, bf2f(hs)));
                zss = fmaf(x, x, zss);
            }
            zhi[t][f] = h8; zlo[t][f] = l8;
        }
    }
    __syncthreads();                                 // chunk0 + s_hb2/s_cnt ready

    float b1[2] = {-1e30f, -1e30f}, b2s[2] = {-1e30f, -1e30f};
    int   k1[2] = {0, 0};

    #pragma unroll 2
    for (int c = 0; c < 16; ++c) {
        const int cur = c & 1;
        short8 n0, n1;
        if (c < 15) {                                // prefetch next chunk early
            n0 = *(const short8*)(img + ((size_t)(c + 1) * 512 + tid) * 8);
            n1 = *(const short8*)(img + ((size_t)(c + 1) * 512 + 256 + tid) * 8);
        }
        const short* bp = &lbuf[cur][lane * 8];
        #pragma unroll
        for (int sub = 0; sub < 2; ++sub) {
            short8 ah0 = *(const short8*)(bp + (0 + 0 + sub) * 512);   // hi f0
            short8 ah1 = *(const short8*)(bp + (0 + 2 + sub) * 512);   // hi f1
            short8 al0 = *(const short8*)(bp + (4 + 0 + sub) * 512);   // lo f0
            short8 al1 = *(const short8*)(bp + (4 + 2 + sub) * 512);   // lo f1
            const int c0 = c * 32 + sub * 16 + g * 4;
            f32x4 hb = *(const f32x4*)&s_hb2[c0];
            #pragma unroll
            for (int t = 0; t < 2; ++t) {
                f32x4 acc = (f32x4){0.f, 0.f, 0.f, 0.f};
                acc = mfma16(ah0, zhi[t][0], acc);
                acc = mfma16(ah1, zhi[t][1], acc);
                acc = mfma16(ah0, zlo[t][0], acc);
                acc = mfma16(ah1, zlo[t][1], acc);
                acc = mfma16(al0, zhi[t][0], acc);
                acc = mfma16(al1, zhi[t][1], acc);
                #pragma unroll
                for (int r = 0; r < 4; ++r) {
                    float sc = acc[r] - hb[r];
                    if (sc > b1[t]) { b2s[t] = b1[t]; b1[t] = sc; k1[t] = c0 + r; }
                    else            { b2s[t] = fmaxf(b2s[t], sc); }
                }
            }
        }
        if (c < 15) {                                // write next chunk (other buf)
            *(short8*)&lbuf[cur ^ 1][(size_t)tid * 8]         = n0;
            *(short8*)&lbuf[cur ^ 1][(size_t)(256 + tid) * 8] = n1;
        }
        __syncthreads();
    }

    // ---- cross-lane merge over the 4 k-groups (xor butterfly -> all lanes) ----
    #pragma unroll
    for (int t = 0; t < 2; ++t) {
        #pragma unroll
        for (int m = 16; m < 64; m <<= 1) {
            float ob = __shfl_xor(b1[t], m);
            float os = __shfl_xor(b2s[t], m);
            int   ok = __shfl_xor(k1[t], m);
            if (ob > b1[t])       { b2s[t] = fmaxf(b1[t], os); b1[t] = ob; k1[t] = ok; }
            else if (ob == b1[t]) { b2s[t] = b1[t]; if (ok < k1[t]) k1[t] = ok; }  // tie -> flag
            else                  { b2s[t] = fmaxf(b2s[t], ob); }
        }
    }

    // ---- enc + flags (lane<16) ----
    if (lane < 16) {
        #pragma unroll
        for (int t = 0; t < 2; ++t) {
            const int tok = tbase + t * 16 + col;
            out[ENC_OFF + tok] = (float)k1[t];
            atomicAdd(&s_cnt[k1[t]], 1);
            if (b1[t] - b2s[t] < EPS) {              // ambiguous: exact re-check
                int slot = atomicAdd(nflag, 1);
                if (slot < FLAG_CAP) flist[slot] = tok;
            }
        }
    }

    // ---- quantized_st: 4 passes, 8 lanes per token row -> contiguous 2KB ----
    #pragma unroll
    for (int p = 0; p < 4; ++p) {
        const int tt   = p >> 1;                     // compile-time under unroll
        const int cidx = (p & 1) * 8 + (lane >> 3);
        const int kq   = __shfl(k1[tt], cidx);       // lane cidx holds col==cidx
        const int tok  = tbase + tt * 16 + cidx;
        const int dc   = (lane & 7) * 8;
        const f32x4* zr4 = (const f32x4*)(z + (size_t)tok * D + dc);
        const f32x4* er4 = (const f32x4*)(ew + (size_t)kq * D + dc);
        f32x4 z0 = zr4[0], z1 = zr4[1], e0 = er4[0], e1 = er4[1], o0, o1;
        #pragma unroll
        for (int r = 0; r < 4; ++r) {
            o0[r] = __fadd_rn(z0[r], __fsub_rn(e0[r], z0[r]));
            o1[r] = __fadd_rn(z1[r], __fsub_rn(e1[r], z1[r]));
        }
        f32x4* op = (f32x4*)(out + Q_OFF + (size_t)tok * D + dc);
        op[0] = o0; op[1] = o1;
    }

    // S = sum ||z||^2 - 2 * sum best_score (loss/mind thresholds are huge)
    float contrib = zss + ((lane < 16) ? -2.f * (b1[0] + b1[1]) : 0.f);
    #pragma unroll
    for (int off = 32; off; off >>= 1) contrib += __shfl_down(contrib, off);
    if (lane == 0) atomicAdd(S, contrib);

    __syncthreads();
    int c0 = s_cnt[tid];       if (c0) atomicAdd(&gcnt[tid], c0);
    int c1 = s_cnt[tid + 256]; if (c1) atomicAdd(&gcnt[tid + 256], c1);
}

// exact numpy-f32 rescan: ONE 64-thread BLOCK PER FLAGGED TOKEN.
// z row = 16 same-address b128 loads; e rows = 16 b128/code -> ~150 VMEM
// per token (was 576 scalar loads). Repairs enc, histogram, Q row.
__global__ __launch_bounds__(64) void vq_refine(
    const float* __restrict__ z, const float* __restrict__ ew,
    const float* __restrict__ b2, float* __restrict__ out,
    int* __restrict__ gcnt, const int* __restrict__ nflag,
    const int* __restrict__ flist)
{
    int nf = *nflag; if (nf > FLAG_CAP) nf = FLAG_CAP;
    if ((int)blockIdx.x >= nf) return;
    const int lane = threadIdx.x;
    const int tok  = flist[blockIdx.x];
    const int old  = (int)out[ENC_OFF + tok];        // read before any write

    const f32x4* zr4 = (const f32x4*)(z + (size_t)tok * D);
    f32x4 zq[16];
    #pragma unroll
    for (int q = 0; q < 16; ++q) zq[q] = zr4[q];

    // a_n in numpy's exact f32 order (d ascending, 8-accumulator pattern)
    float ra[8];
    #pragma unroll
    for (int q = 0; q < 16; ++q) {
        #pragma unroll
        for (int rr = 0; rr < 4; ++rr) {
            int j = (q & 1) * 4 + rr;
            float x = zq[q][rr];
            if (q < 2) ra[j] = __fmul_rn(x, x);
            else       ra[j] = __fadd_rn(ra[j], __fmul_rn(x, x));
        }
    }
    float lsum = __fadd_rn(__fadd_rn(ra[0], ra[1]), __fadd_rn(ra[2], ra[3]));
    float hsum = __fadd_rn(__fadd_rn(ra[4], ra[5]), __fadd_rn(ra[6], ra[7]));
    const float an = __fadd_rn(lsum, hsum);

    float bd = 1e30f; int bk = 0;
    #pragma unroll 1
    for (int j = 0; j < 8; ++j) {
        const int cc = j * 64 + lane;
        const f32x4* er4 = (const f32x4*)(ew + (size_t)cc * D);
        float gacc = 0.f;
        #pragma unroll
        for (int q = 0; q < 16; ++q) {
            f32x4 ev = er4[q];
            #pragma unroll
            for (int rr = 0; rr < 4; ++rr) gacc = fmaf(zq[q][rr], ev[rr], gacc);
        }
        float dd = fmaf(-2.f, gacc, __fadd_rn(an, b2[cc]));
        if (dd < bd) { bd = dd; bk = cc; }           // lane-ascending codes
    }
    #pragma unroll
    for (int off = 32; off; off >>= 1) {             // min-d, min-index
        float obd = __shfl_down(bd, off);
        int   obk = __shfl_down(bk, off);
        if (obd < bd || (obd == bd && obk < bk)) { bd = obd; bk = obk; }
    }
    bk = __shfl(bk, 0);

    if (bk != old) {
        float zv = z[(size_t)tok * D + lane];
        float ev = ew[(size_t)bk * D + lane];
        out[Q_OFF + (size_t)tok * D + lane] = __fadd_rn(zv, __fsub_rn(ev, zv));
        if (lane == 0) {
            out[ENC_OFF + tok] = (float)bk;
            atomicAdd(&gcnt[bk], 1);
            atomicAdd(&gcnt[old], -1);
        }
    }
}

__global__ void vq_fin(const float* __restrict__ S, const int* __restrict__ gcnt,
                       float* __restrict__ out)
{
    __shared__ float red[8];
    int t = threadIdx.x;               // 512 threads, one per code
    float p = (float)gcnt[t] * (1.f / (float)N_TOK);
    float term = p * logf(p + 1e-10f);
    #pragma unroll
    for (int off = 32; off; off >>= 1) term += __shfl_down(term, off);
    if ((t & 63) == 0) red[t >> 6] = term;
    __syncthreads();
    if (t == 0) {
        float s = 0.f;
        #pragma unroll
        for (int i = 0; i < 8; ++i) s += red[i];
        float Sv = S[0];
        out[PERP_OFF] = expf(-s);
        out[LOSS_OFF] = 1.25f * Sv * (1.f / (float)(N_TOK * D));
        out[MIND_OFF] = Sv * (1.f / (float)N_TOK);
    }
}

extern "C" void kernel_launch(void* const* d_in, const int* in_sizes, int n_in,
                              void* d_out, int out_size, void* d_ws, size_t ws_size,
                              hipStream_t stream)
{
    const float* z  = (const float*)d_in[0];
    const float* ew = (const float*)d_in[1];
    float* out = (float*)d_out;
    float* wsf = (float*)d_ws;

    float* Sp    = wsf + 512;
    int*   gcnt  = (int*)(wsf + 514);
    int*   nflag = (int*)(wsf + 1026);
    int*   flist = (int*)(wsf + 1028);
    short* img   = (short*)(wsf + 16384);    // 128 KB bf16 image

    // zero S, counts, flag counter each call (graph replays don't re-poison)
    hipMemsetAsync(wsf + 512, 0, 516 * sizeof(float), stream);

    vq_prep_b2 <<<2, 256, 0, stream>>>(ew, wsf);
    vq_prep_img<<<32, 256, 0, stream>>>(ew, img);
    vq_screen  <<<N_TOK / TPB, BLK, 0, stream>>>(z, ew, img, wsf, out, Sp, gcnt, nflag, flist);
    vq_refine  <<<FLAG_CAP, 64, 0, stream>>>(z, ew, wsf, out, gcnt, nflag, flist);
    vq_fin     <<<1, 512, 0, stream>>>(Sp, gcnt, out);
}